// Round 2
// baseline (153.167 us; speedup 1.0000x reference)
//
#include <hip/hip_runtime.h>
#include <math.h>

// Problem: B=2, T=4096, N=4, DIM=2048
//   rows = B*T*N = 32768 rows of DIM f32 (256 MiB)
//   out  = H_pre [32768] ++ H_post [32768] ++ H_res [B,T,4,4] (131072) f32
//
// Fusion: dot(theta, x_tilde) = rstd * sum_c (theta[c]*w[c]) * x[c]
// -> one pass over x computes sum(x^2) and all 6 folded dots.
//
// Round-2 structure: register double-buffer prefetch across pair iterations.
// Each wave owns 4 row-pairs; while computing pair k, the 16 float4 loads of
// pair k+1 are in flight (latency-bound fix; round 1 measured 3.4 waves/CU
// resident and ~10% load duty -> 859 GB/s).
#define DIM     2048
#define NROWS   32768
#define NPAIRS  16384
#define EPS_RMS 1e-6f
#define NTH     6

__device__ __forceinline__ float fast_tanh(float x) {
    // tanh(x) = 1 - 2/(exp(2x)+1); exact at +/-inf, ~1e-7 rel err. h ~ O(1).
    return 1.0f - 2.0f / (__expf(2.0f * x) + 1.0f);
}

__device__ __forceinline__ void load_pair(const float4* __restrict__ xb, int lane,
                                          float4 (&A)[8], float4 (&B)[8]) {
#pragma unroll
    for (int j = 0; j < 8; ++j) {
        A[j] = xb[j * 64 + lane];          // row 2p
        B[j] = xb[512 + j * 64 + lane];    // row 2p+1
    }
}

__global__ __launch_bounds__(256, 2) void hcmaps_kernel(
    const float* __restrict__ x,          // [NROWS, DIM]
    const float* __restrict__ w,          // [DIM]
    const float* __restrict__ alpha_pre_p,
    const float* __restrict__ alpha_post_p,
    const float* __restrict__ alpha_res_p,
    const float* __restrict__ theta_pre,  // [DIM]
    const float* __restrict__ theta_post, // [DIM]
    const float* __restrict__ theta_res,  // [4, DIM]
    const float* __restrict__ b_pre,      // [4]
    const float* __restrict__ b_post,     // [4]
    const float* __restrict__ b_res,      // [16] row-major [i][n]
    float* __restrict__ out)              // [196608]
{
    __shared__ float s_wt[NTH * DIM];     // 48 KiB: w*theta for all 6 vectors

    // ---- fold w*theta into LDS (once per block) ----
    for (int c = threadIdx.x * 4; c < DIM; c += 256 * 4) {
        const float4 wv = *(const float4*)(w + c);
        const float4 tp = *(const float4*)(theta_pre + c);
        const float4 tq = *(const float4*)(theta_post + c);
        *(float4*)(s_wt + 0 * DIM + c) =
            make_float4(wv.x * tp.x, wv.y * tp.y, wv.z * tp.z, wv.w * tp.w);
        *(float4*)(s_wt + 1 * DIM + c) =
            make_float4(wv.x * tq.x, wv.y * tq.y, wv.z * tq.z, wv.w * tq.w);
#pragma unroll
        for (int i = 0; i < 4; ++i) {
            const float4 tr = *(const float4*)(theta_res + i * DIM + c);
            *(float4*)(s_wt + (2 + i) * DIM + c) =
                make_float4(wv.x * tr.x, wv.y * tr.y, wv.z * tr.z, wv.w * tr.w);
        }
    }
    __syncthreads();

    const int lane = threadIdx.x & 63;
    const int wid  = blockIdx.x * 4 + (threadIdx.x >> 6);   // 0..4095

    const float apre  = alpha_pre_p[0];
    const float apost = alpha_post_p[0];
    const float ares  = alpha_res_p[0];

    // process: full per-pair compute + reduce + epilogue from registers
    auto process = [&](const float4 (&A)[8], const float4 (&B)[8], int p) {
        float ssa = 0.f, ssb = 0.f;
        float da[6] = {0.f, 0.f, 0.f, 0.f, 0.f, 0.f};
        float db[6] = {0.f, 0.f, 0.f, 0.f, 0.f, 0.f};
#pragma unroll
        for (int j = 0; j < 8; ++j) {
            const int c = (j * 64 + lane) * 4;
            const float4 Av = A[j];
            const float4 Bv = B[j];
            ssa += Av.x * Av.x + Av.y * Av.y + Av.z * Av.z + Av.w * Av.w;
            ssb += Bv.x * Bv.x + Bv.y * Bv.y + Bv.z * Bv.z + Bv.w * Bv.w;
#pragma unroll
            for (int v = 0; v < 6; ++v) {
                const float4 t = *(const float4*)(s_wt + v * DIM + c);
                da[v] += t.x * Av.x + t.y * Av.y + t.z * Av.z + t.w * Av.w;
                db[v] += t.x * Bv.x + t.y * Bv.y + t.z * Bv.z + t.w * Bv.w;
            }
        }
        // butterfly reduce 14 scalars across the 64-lane wave
#pragma unroll
        for (int off = 32; off > 0; off >>= 1) {
            ssa += __shfl_xor(ssa, off);
            ssb += __shfl_xor(ssb, off);
#pragma unroll
            for (int v = 0; v < 6; ++v) {
                da[v] += __shfl_xor(da[v], off);
                db[v] += __shfl_xor(db[v], off);
            }
        }
        if (lane < 2) {
            const float ss = (lane == 0) ? ssa : ssb;
            float d[6];
#pragma unroll
            for (int v = 0; v < 6; ++v) d[v] = (lane == 0) ? da[v] : db[v];
            const int r   = p * 2 + lane;
            const int n   = r & 3;
            const int rbt = r >> 2;
            const float rstd = rsqrtf(ss * (1.0f / DIM) + EPS_RMS);
            out[r]         = apre  * fast_tanh(d[0] * rstd) + b_pre[n];
            out[NROWS + r] = apost * fast_tanh(d[1] * rstd) + b_post[n];
            float* res = out + 2 * NROWS + rbt * 16 + n;
#pragma unroll
            for (int i = 0; i < 4; ++i)
                res[i * 4] = ares * fast_tanh(d[2 + i] * rstd) + b_res[i * 4 + n];
        }
    };

    const float4* xb = (const float4*)x;
    float4 A0[8], B0[8], A1[8], B1[8];

    // 4 pairs per wave: wid, wid+4096, wid+8192, wid+12288 (all in-range).
    // Double-buffered register prefetch: next pair's loads in flight across
    // the current pair's compute+reduce+epilogue.
    load_pair(xb + (size_t)wid * 1024, lane, A0, B0);
    for (int k = 0; k < 2; ++k) {
        const int p = wid + k * 8192;
        load_pair(xb + (size_t)(p + 4096) * 1024, lane, A1, B1);
        process(A0, B0, p);
        if (k == 0)
            load_pair(xb + (size_t)(p + 8192) * 1024, lane, A0, B0);
        process(A1, B1, p + 4096);
    }
}

extern "C" void kernel_launch(void* const* d_in, const int* in_sizes, int n_in,
                              void* d_out, int out_size, void* d_ws, size_t ws_size,
                              hipStream_t stream) {
    const float* x          = (const float*)d_in[0];
    const float* rms_weight = (const float*)d_in[1];
    const float* alpha_pre  = (const float*)d_in[2];
    const float* alpha_post = (const float*)d_in[3];
    const float* alpha_res  = (const float*)d_in[4];
    const float* theta_pre  = (const float*)d_in[5];
    const float* theta_post = (const float*)d_in[6];
    const float* theta_res  = (const float*)d_in[7];
    const float* b_pre      = (const float*)d_in[8];
    const float* b_post     = (const float*)d_in[9];
    const float* b_res      = (const float*)d_in[10];
    float* out = (float*)d_out;

    dim3 grid(1024);   // 4096 waves x 4 pairs = 16384 pairs
    dim3 block(256);
    hipLaunchKernelGGL(hcmaps_kernel, grid, block, 0, stream,
                       x, rms_weight, alpha_pre, alpha_post, alpha_res,
                       theta_pre, theta_post, theta_res,
                       b_pre, b_post, b_res, out);
}